// Round 8
// baseline (110.452 us; speedup 1.0000x reference)
//
#include <hip/hip_runtime.h>
#include <hip/hip_bf16.h>
#include <hip/hip_cooperative_groups.h>
#include <stdint.h>

namespace cg = cooperative_groups;

// ---------------------------------------------------------------------------
// GraphicalBranch: out[r] = relu(x[row_r] @ W_self + (S_{b_r} @ W_nbr) + bias)
//   S_b = sum of the 28 pair-node rows of sample b
//   row_r = b*28 + pidx(pmin,pmax), pidx = 7i - i(i-1)/2 + (j-i-1)  [analytic]
// SINGLE cooperative kernel, 512 blocks x 256 thr (2/CU co-resident):
//   Phase A: each block: 2 samples (S-sum, interleaved loads; gather->Abf)
//            + one 32x32 W^T piece (512 pieces = Wself+Wnbr exactly)
//   grid.sync()
//   Phase B: fused GEMM, block = 96 rows x 128 cols (5 rel strips @Wself^T +
//            1 S strip @Wnbr^T -> T), 2-phase dbuf, counted vmcnt, XOR swizzle
// Fallback (if cooperative launch fails): same two phases as separate kernels.
// ---------------------------------------------------------------------------

typedef __bf16 bf16_t;
typedef __bf16 bf16x8 __attribute__((ext_vector_type(8)));
typedef __bf16 bf16x4 __attribute__((ext_vector_type(4)));
typedef float  f32x4  __attribute__((ext_vector_type(4)));

#define D_DIM 512
#define NC2   28
#define NOBJ  8
#define MAXREL 10
#define B_SAMP 1024
#define OUTROWS (B_SAMP * MAXREL)

#define SA_BYTES 6144               // 96 rows * 64 B
#define SB_BYTES 16384              // 2 mats * 128 rows * 64 B
#define POOL_BYTES (2 * (SA_BYTES + SB_BYTES))   // 45056

__device__ __forceinline__ void gload_lds16(const void* g, void* l) {
  __builtin_amdgcn_global_load_lds(
      (const __attribute__((address_space(1))) unsigned int*)g,
      (__attribute__((address_space(3))) unsigned int*)l, 16, 0, 0);
}

// --- Phase A: 2 samples (sum + gather) + one 32x32 W^T piece per block -----
__device__ __forceinline__ void phaseA_body(
    unsigned char* pool, int bid, int tid,
    const float* __restrict__ x, const float* __restrict__ Wself,
    const float* __restrict__ Wnbr, const int* __restrict__ pairs,
    bf16_t* __restrict__ Sbf, bf16_t* __restrict__ Abf,
    bf16_t* __restrict__ Wst, bf16_t* __restrict__ Wnt)
{
  int*    rr     = (int*)pool;                  // [20]
  float4* oddsum = (float4*)(pool + 128);       // [2][128]
  float*  tile   = (float*)(pool + 128 + 4096); // [32][33]

  if (tid < 2 * MAXREL) {
    int sm = bid * 2 + tid / MAXREL, j = tid % MAXREL;
    int p0 = pairs[sm * MAXREL * 2 + j * 2 + 0];
    int p1 = pairs[sm * MAXREL * 2 + j * 2 + 1];
    int pmin = min(p0, p1), pmax = max(p0, p1);
    rr[tid] = 7 * pmin - (pmin * (pmin - 1)) / 2 + (pmax - pmin - 1);
  }
  __syncthreads();

  const int h = tid >> 7, c = tid & 127;        // half, float4-col
  const int sm0 = bid * 2;
  const float4* x40 = (const float4*)(x + (size_t)sm0 * NC2 * D_DIM);
  const float4* x41 = x40 + NC2 * 128;

  float4 a0 = {0.f,0.f,0.f,0.f}, a1 = {0.f,0.f,0.f,0.f};
  #pragma unroll
  for (int rp = 0; rp < NC2 / 2; ++rp) {        // interleave both samples
    float4 v0 = x40[(rp * 2 + h) * 128 + c];
    float4 v1 = x41[(rp * 2 + h) * 128 + c];
    a0.x += v0.x; a0.y += v0.y; a0.z += v0.z; a0.w += v0.w;
    a1.x += v1.x; a1.y += v1.y; a1.z += v1.z; a1.w += v1.w;
  }
  if (h) { oddsum[c] = a0; oddsum[128 + c] = a1; }
  __syncthreads();
  if (!h) {
    float4 b0 = oddsum[c], b1 = oddsum[128 + c];
    bf16x4 o0 = { (bf16_t)(a0.x + b0.x), (bf16_t)(a0.y + b0.y),
                  (bf16_t)(a0.z + b0.z), (bf16_t)(a0.w + b0.w) };
    bf16x4 o1 = { (bf16_t)(a1.x + b1.x), (bf16_t)(a1.y + b1.y),
                  (bf16_t)(a1.z + b1.z), (bf16_t)(a1.w + b1.w) };
    *(bf16x4*)(Sbf + (size_t)sm0 * D_DIM + c * 4) = o0;
    *(bf16x4*)(Sbf + (size_t)(sm0 + 1) * D_DIM + c * 4) = o1;
  }
  // gather pass (rows just streamed -> L1/L2 hot); handles duplicate pairs
  #pragma unroll
  for (int j = h; j < MAXREL; j += 2) {
    float4 v0 = x40[rr[j] * 128 + c];
    float4 v1 = x41[rr[10 + j] * 128 + c];
    bf16x4 o0 = { (bf16_t)v0.x, (bf16_t)v0.y, (bf16_t)v0.z, (bf16_t)v0.w };
    bf16x4 o1 = { (bf16_t)v1.x, (bf16_t)v1.y, (bf16_t)v1.z, (bf16_t)v1.w };
    *(bf16x4*)(Abf + (size_t)(sm0 * MAXREL + j) * D_DIM + c * 4) = o0;
    *(bf16x4*)(Abf + (size_t)((sm0 + 1) * MAXREL + j) * D_DIM + c * 4) = o1;
  }
  // one 32x32 W transpose piece: bid -> {mat, 16x16 grid of pieces}
  {
    int mat = bid >> 8, pc = bid & 255;
    int k0 = (pc & 15) * 32, n1 = (pc >> 4) * 32;
    const float* W  = mat ? Wnbr : Wself;
    bf16_t*      Wt = mat ? Wnt  : Wst;
    int tx = tid & 31, ty = tid >> 5;
    #pragma unroll
    for (int i = 0; i < 32; i += 8)
      tile[(ty + i) * 33 + tx] = W[(size_t)(k0 + ty + i) * D_DIM + n1 + tx];
    __syncthreads();
    #pragma unroll
    for (int i = 0; i < 32; i += 8)
      Wt[(size_t)(n1 + ty + i) * D_DIM + k0 + tx] = (bf16_t)tile[tx * 33 + ty + i];
  }
}

// --- Phase B: fused GEMM (96x128 block, counted vmcnt, XOR swizzle) --------
__device__ __forceinline__ void phaseB_body(
    unsigned char* pool, int bid, int tid,
    const bf16_t* __restrict__ Abf, const bf16_t* __restrict__ Sbf,
    const bf16_t* __restrict__ Wst, const bf16_t* __restrict__ Wnt,
    const float* __restrict__ bias, float* __restrict__ out)
{
  const int w = tid >> 6, l = tid & 63;
  const int kg = l >> 4, lr = l & 15;
  const int bx = bid & 127, by = bid >> 7;     // by-blocks of a bx: same XCD
  const int n0 = by * 128;
  const int arow0 = bx * 80, srow0 = bx * 8;

  f32x4 acc[6][2] = {};

  // stage one 32-wide K slab: A 384 chunks (slots 0-5), B 1024 (slots 6-21)
  // per-wave issues: w0,w1 -> 6; w2,w3 -> 5
  auto STAGE = [&](int bsel, int k0) {
    bf16_t* aB = (bf16_t*)(pool + bsel * SA_BYTES);
    bf16_t* bB = (bf16_t*)(pool + 2 * SA_BYTES + bsel * SB_BYTES);
    #pragma unroll
    for (int r = 0; r < 6; ++r) {
      int slot = r * 4 + w;
      if (slot < 6) {
        int cch = slot * 64 + l;
        int row = cch >> 2, ch = cch & 3;
        int sch = ch ^ ((row >> 1) & 3);
        const bf16_t* g = (row < 80)
            ? Abf + (size_t)(arow0 + row) * D_DIM + k0 + sch * 8
            : Sbf + (size_t)(srow0 + (row & 7)) * D_DIM + k0 + sch * 8;
        gload_lds16(g, aB + (size_t)cch * 8);
      } else if (slot < 22) {
        int cch = (slot - 6) * 64 + l;
        int mat = cch >> 9, rc = cch & 511;
        int row = rc >> 2, ch = rc & 3;
        int sch = ch ^ ((row >> 1) & 3);
        const bf16_t* W = mat ? Wnt : Wst;
        gload_lds16(W + (size_t)(n0 + row) * D_DIM + k0 + sch * 8,
                    bB + (size_t)cch * 8);
      }
    }
  };

  STAGE(0, 0);
  asm volatile("s_waitcnt vmcnt(0)" ::: "memory");
  __builtin_amdgcn_s_barrier();

  const int xorc = (kg ^ ((lr >> 1) & 3)) * 8;
  int cur = 0;
  #pragma unroll
  for (int t = 0; t < 16; ++t) {
    if (t < 15) {
      STAGE(cur ^ 1, (t + 1) * 32);            // prefetch stays in flight
      if (w < 2) asm volatile("s_waitcnt vmcnt(6)" ::: "memory");
      else       asm volatile("s_waitcnt vmcnt(5)" ::: "memory");
    } else {
      asm volatile("s_waitcnt vmcnt(0)" ::: "memory");
    }
    __builtin_amdgcn_s_barrier();

    const bf16_t* aC = (const bf16_t*)(pool + cur * SA_BYTES);
    const bf16_t* bC = (const bf16_t*)(pool + 2 * SA_BYTES + cur * SB_BYTES);
    bf16x8 af[6], bsf[2], bnf[2];
    #pragma unroll
    for (int s = 0; s < 6; ++s)
      af[s] = *(const bf16x8*)(aC + (s * 16 + lr) * 32 + xorc);
    #pragma unroll
    for (int u = 0; u < 2; ++u) {
      bsf[u] = *(const bf16x8*)(bC + (w * 32 + u * 16 + lr) * 32 + xorc);
      bnf[u] = *(const bf16x8*)(bC + 4096 + (w * 32 + u * 16 + lr) * 32 + xorc);
    }
    __builtin_amdgcn_s_setprio(1);
    #pragma unroll
    for (int s = 0; s < 5; ++s)
      #pragma unroll
      for (int u = 0; u < 2; ++u)
        acc[s][u] = __builtin_amdgcn_mfma_f32_16x16x32_bf16(af[s], bsf[u], acc[s][u], 0, 0, 0);
    acc[5][0] = __builtin_amdgcn_mfma_f32_16x16x32_bf16(af[5], bnf[0], acc[5][0], 0, 0, 0);
    acc[5][1] = __builtin_amdgcn_mfma_f32_16x16x32_bf16(af[5], bnf[1], acc[5][1], 0, 0, 0);
    __builtin_amdgcn_s_setprio(0);

    __builtin_amdgcn_s_barrier();              // readers done before reuse
    cur ^= 1;
  }

  // T tile -> per-wave LDS (pool reuse, fenced by final barrier)
  // C/D layout: col = l&15, row = (l>>4)*4 + reg  [m89-verified]
  float* Tex = (float*)pool;                   // [4][16][33]
  #pragma unroll
  for (int u = 0; u < 2; ++u)
    #pragma unroll
    for (int reg = 0; reg < 4; ++reg)
      Tex[(w * 16 + kg * 4 + reg) * 33 + u * 16 + lr] = acc[5][u][reg];
  __syncthreads();

  const float bv0 = bias[n0 + w * 32 + lr];
  const float bv1 = bias[n0 + w * 32 + 16 + lr];
  #pragma unroll
  for (int s = 0; s < 5; ++s) {
    #pragma unroll
    for (int u = 0; u < 2; ++u) {
      #pragma unroll
      for (int reg = 0; reg < 4; ++reg) {
        int rloc = s * 16 + kg * 4 + reg;      // 0..79
        int ls = rloc / MAXREL;                // local sample 0..7
        int cc = u * 16 + lr;                  // col within wave's 32
        float v = acc[s][u][reg] + Tex[(w * 16 + ls) * 33 + cc] + (u ? bv1 : bv0);
        out[(size_t)(arow0 + rloc) * D_DIM + n0 + w * 32 + cc] = fmaxf(v, 0.0f);
      }
    }
  }
}

// --- single cooperative kernel ---------------------------------------------
__global__ __launch_bounds__(256, 2) void fused_all_kernel(
    const float* x, const float* Wself, const float* Wnbr,
    const float* bias, const int* pairs,
    bf16_t* Sbf, bf16_t* Abf, bf16_t* Wst, bf16_t* Wnt, float* out)
{
  __shared__ __align__(16) unsigned char pool[POOL_BYTES];
  phaseA_body(pool, blockIdx.x, threadIdx.x, x, Wself, Wnbr, pairs,
              Sbf, Abf, Wst, Wnt);
  cg::this_grid().sync();
  phaseB_body(pool, blockIdx.x, threadIdx.x, Abf, Sbf, Wst, Wnt, bias, out);
}

// --- fallback: same phases as two regular kernels --------------------------
__global__ __launch_bounds__(256) void prepA_kernel(
    const float* x, const float* Wself, const float* Wnbr, const int* pairs,
    bf16_t* Sbf, bf16_t* Abf, bf16_t* Wst, bf16_t* Wnt)
{
  __shared__ __align__(16) unsigned char pool[16384];
  phaseA_body(pool, blockIdx.x, threadIdx.x, x, Wself, Wnbr, pairs,
              Sbf, Abf, Wst, Wnt);
}

__global__ __launch_bounds__(256, 2) void gemmB_kernel(
    const bf16_t* Abf, const bf16_t* Sbf, const bf16_t* Wst,
    const bf16_t* Wnt, const float* bias, float* out)
{
  __shared__ __align__(16) unsigned char pool[POOL_BYTES];
  phaseB_body(pool, blockIdx.x, threadIdx.x, Abf, Sbf, Wst, Wnt, bias, out);
}

extern "C" void kernel_launch(void* const* d_in, const int* in_sizes, int n_in,
                              void* d_out, int out_size, void* d_ws, size_t ws_size,
                              hipStream_t stream) {
  const float* x     = (const float*)d_in[0];   // [28672, 512]
  const float* Wself = (const float*)d_in[1];   // [512, 512]
  const float* Wnbr  = (const float*)d_in[2];   // [512, 512]
  const float* bias  = (const float*)d_in[3];   // [512]
  const int*   pairs = (const int*)d_in[5];     // [1024, 10, 2]

  char* ws = (char*)d_ws;
  size_t off = 0;
  bf16_t* Sbf = (bf16_t*)(ws + off); off += (size_t)B_SAMP * D_DIM * 2;
  bf16_t* Wst = (bf16_t*)(ws + off); off += (size_t)D_DIM * D_DIM * 2;
  bf16_t* Wnt = (bf16_t*)(ws + off); off += (size_t)D_DIM * D_DIM * 2;
  bf16_t* Abf = (bf16_t*)(ws + off); off += (size_t)OUTROWS * D_DIM * 2;
  float*  outp = (float*)d_out;

  void* args[] = { (void*)&x, (void*)&Wself, (void*)&Wnbr, (void*)&bias,
                   (void*)&pairs, (void*)&Sbf, (void*)&Abf, (void*)&Wst,
                   (void*)&Wnt, (void*)&outp };
  hipError_t e = hipLaunchCooperativeKernel(
      (const void*)fused_all_kernel, dim3(512), dim3(256), args, 0, stream);
  if (e != hipSuccess) {
    // fallback: two regular launches (same math)
    prepA_kernel<<<512, 256, 0, stream>>>(x, Wself, Wnbr, pairs,
                                          Sbf, Abf, Wst, Wnt);
    gemmB_kernel<<<512, 256, 0, stream>>>(Abf, Sbf, Wst, Wnt, bias, outp);
  }
}

// Round 9
// 40.334 us; speedup vs baseline: 2.7385x; 2.7385x over previous
//
#include <hip/hip_runtime.h>
#include <hip/hip_bf16.h>
#include <stdint.h>

// ---------------------------------------------------------------------------
// GraphicalBranch: out[r] = relu(x[row_r] @ W_self + (S_{b_r} @ W_nbr) + bias)
//   S_b = sum of the 28 pair-node rows of sample b
//   row_r = b*28 + pidx(pmin,pmax), pidx = 7i - i(i-1)/2 + (j-i-1)  [analytic]
// K1 prep (1536 blks): streaming S-sum (float4) + L2-hot gather->Abf | W^T bf16
// K2 fused GEMM (128x8 blks, 64-col tiles):
//   A (96 rows: 5 rel strips + S strip) via LDS (shared 4x by waves),
//   B (W_self^T/W_nbr^T frags) DIRECT global->reg (zero inter-wave sharing ->
//   LDS staging was pure overhead), both double-buffered, counted vmcnt,
//   XOR-swizzled A-LDS. Epilogue: out = relu(acc + T[sample] + bias).
// ---------------------------------------------------------------------------

typedef __bf16 bf16_t;
typedef __bf16 bf16x8 __attribute__((ext_vector_type(8)));
typedef __bf16 bf16x4 __attribute__((ext_vector_type(4)));
typedef float  f32x4  __attribute__((ext_vector_type(4)));

#define D_DIM 512
#define NC2   28
#define NOBJ  8
#define MAXREL 10
#define B_SAMP 1024
#define OUTROWS (B_SAMP * MAXREL)

__device__ __forceinline__ void gload_lds16(const void* g, void* l) {
  __builtin_amdgcn_global_load_lds(
      (const __attribute__((address_space(1))) unsigned int*)g,
      (__attribute__((address_space(3))) unsigned int*)l, 16, 0, 0);
}

// --- K1: fused prep --------------------------------------------------------
// blocks [0,1024):     S[b] = sum of 28 rows (clean streaming) -> bf16;
//                      then gather the 10 rel rows (L1/L2-hot) -> Abf
// blocks [1024,1536):  W transpose+convert (256 blocks per matrix)
__global__ __launch_bounds__(256) void prep_kernel(
    const float* __restrict__ x, const float* __restrict__ Wself,
    const float* __restrict__ Wnbr, const int* __restrict__ pairs,
    bf16_t* __restrict__ Sbf, bf16_t* __restrict__ Abf,
    bf16_t* __restrict__ Wst, bf16_t* __restrict__ Wnt)
{
  const int blk = blockIdx.x, tid = threadIdx.x;
  if (blk < B_SAMP) {
    __shared__ int rel_row[MAXREL];
    __shared__ float4 oddsum[128];
    if (tid < MAXREL) {
      int p0 = pairs[blk * MAXREL * 2 + tid * 2 + 0];
      int p1 = pairs[blk * MAXREL * 2 + tid * 2 + 1];
      int pmin = min(p0, p1), pmax = max(p0, p1);
      rel_row[tid] = 7 * pmin - (pmin * (pmin - 1)) / 2 + (pmax - pmin - 1);
    }
    __syncthreads();

    const int h = tid >> 7, c = tid & 127;        // half, float4-col
    const float4* x4 = (const float4*)(x + (size_t)blk * NC2 * D_DIM);
    float4 a = {0.f, 0.f, 0.f, 0.f};
    #pragma unroll
    for (int rp = 0; rp < NC2 / 2; ++rp) {        // clean streaming sum
      float4 v = x4[(rp * 2 + h) * 128 + c];
      a.x += v.x; a.y += v.y; a.z += v.z; a.w += v.w;
    }
    if (h) oddsum[c] = a;
    __syncthreads();
    if (!h) {
      float4 b = oddsum[c];
      bf16x4 o = { (bf16_t)(a.x + b.x), (bf16_t)(a.y + b.y),
                   (bf16_t)(a.z + b.z), (bf16_t)(a.w + b.w) };
      *(bf16x4*)(Sbf + (size_t)blk * D_DIM + c * 4) = o;
    }
    // gather pass: rows just streamed -> L1/L2 hot
    #pragma unroll
    for (int j = h; j < MAXREL; j += 2) {
      float4 v = x4[rel_row[j] * 128 + c];
      bf16x4 o = { (bf16_t)v.x, (bf16_t)v.y, (bf16_t)v.z, (bf16_t)v.w };
      *(bf16x4*)(Abf + (size_t)(blk * MAXREL + j) * D_DIM + c * 4) = o;
    }
  } else {
    __shared__ float tile[32][33];
    const int t = blk - B_SAMP;
    const float* W  = (t & 256) ? Wnbr : Wself;
    bf16_t*     Wt  = (t & 256) ? Wnt  : Wst;
    const int r = t & 255;
    const int k0 = (r & 15) * 32, n0 = (r >> 4) * 32;
    const int tx = tid & 31, ty = tid >> 5;
    #pragma unroll
    for (int i = 0; i < 32; i += 8)
      tile[ty + i][tx] = W[(size_t)(k0 + ty + i) * D_DIM + n0 + tx];
    __syncthreads();
    #pragma unroll
    for (int i = 0; i < 32; i += 8)
      Wt[(size_t)(n0 + ty + i) * D_DIM + k0 + tx] = (bf16_t)tile[tx][ty + i];
  }
}

// --- K2: fused GEMM, A-LDS dbuf + B-in-reg dbuf, counted vmcnt -------------
// Block (bx, by): 8 samples, out rows [bx*80, +80), cols [by*64, +64).
// A strips 0..4 = 80 rel rows (@Wst); strip 5 = 8 S rows dup-padded (@Wnt).
// Wave w owns cols [by*64 + w*16, +16).
// A-LDS chunks (16B): LDS[row][c] = G[row][c ^ ((row>>1)&3)]  (involution).
#define SA_BYTES 6144              // 96 rows * 64 B

#define DS_MFMA(AF, BS, BN) do {                                              \
    _Pragma("unroll")                                                         \
    for (int s_ = 0; s_ < 6; ++s_)                                            \
      AF[s_] = *(const bf16x8*)(aC + (s_ * 16 + lr) * 32 + xorc);             \
    _Pragma("unroll")                                                         \
    for (int s_ = 0; s_ < 5; ++s_)                                            \
      acc[s_] = __builtin_amdgcn_mfma_f32_16x16x32_bf16(AF[s_], BS, acc[s_], 0, 0, 0); \
    acc[5] = __builtin_amdgcn_mfma_f32_16x16x32_bf16(AF[5], BN, acc[5], 0, 0, 0); \
  } while (0)

__global__ __launch_bounds__(256, 5) void fused_gemm_kernel(
    const bf16_t* __restrict__ Abf, const bf16_t* __restrict__ Sbf,
    const bf16_t* __restrict__ Wst, const bf16_t* __restrict__ Wnt,
    const float* __restrict__ bias, float* __restrict__ out)
{
  __shared__ __align__(16) unsigned char pool[2 * SA_BYTES];

  const int tid = threadIdx.x;
  const int w = tid >> 6, l = tid & 63;
  const int kg = l >> 4, lr = l & 15;
  const int n0w = blockIdx.y * 64 + w * 16;    // wave col base
  const int arow0 = blockIdx.x * 80;
  const int srow0 = blockIdx.x * 8;

  f32x4 acc[6] = {};

  // stage A slab (96 rows x 32 k = 384 x 16B chunks): w0,w1 -> 2; w2,w3 -> 1
  auto STAGE = [&](int bsel, int k0) {
    bf16_t* aB = (bf16_t*)(pool + bsel * SA_BYTES);
    #pragma unroll
    for (int r = 0; r < 2; ++r) {
      int slot = r * 4 + w;
      if (slot < 6) {
        int c = slot * 64 + l;
        int row = c >> 2, ch = c & 3;
        int sch = ch ^ ((row >> 1) & 3);
        const bf16_t* g = (row < 80)
            ? Abf + (size_t)(arow0 + row) * D_DIM + k0 + sch * 8
            : Sbf + (size_t)(srow0 + (row & 7)) * D_DIM + k0 + sch * 8;
        gload_lds16(g, aB + (size_t)c * 8);
      }
    }
  };

  // B fragment streams: per-lane row = wave col (n0w + lr), k chunk = kg
  const bf16_t* pBs = Wst + (size_t)(n0w + lr) * D_DIM + kg * 8;
  const bf16_t* pBn = Wnt + (size_t)(n0w + lr) * D_DIM + kg * 8;

  bf16x8 bsX, bnX, bsY, bnY, af[6];

  STAGE(0, 0);
  bsX = *(const bf16x8*)(pBs);
  bnX = *(const bf16x8*)(pBn);
  asm volatile("s_waitcnt vmcnt(0)" ::: "memory");
  __builtin_amdgcn_s_barrier();

  const int xorc = (kg ^ ((lr >> 1) & 3)) * 8;   // swizzled chunk offset
  int cur = 0;
  #pragma unroll
  for (int t = 0; t < 16; t += 2) {
    // ---- even step: compute buf cur with X; prefetch (t+1) into cur^1 / Y
    if (t + 1 < 16) {
      STAGE(cur ^ 1, (t + 1) * 32);
      bsY = *(const bf16x8*)(pBs + (t + 1) * 32);
      bnY = *(const bf16x8*)(pBn + (t + 1) * 32);
      // wait current A-slab + B-X landed; keep this step's issues in flight
      if (w < 2) asm volatile("s_waitcnt vmcnt(4)" ::: "memory");
      else       asm volatile("s_waitcnt vmcnt(3)" ::: "memory");
    } else {
      asm volatile("s_waitcnt vmcnt(0)" ::: "memory");
    }
    __builtin_amdgcn_s_barrier();
    {
      const bf16_t* aC = (const bf16_t*)(pool + cur * SA_BYTES);
      DS_MFMA(af, bsX, bnX);
    }
    __builtin_amdgcn_s_barrier();
    cur ^= 1;

    // ---- odd step: compute buf cur with Y; prefetch (t+2) into cur^1 / X
    if (t + 2 < 16) {
      STAGE(cur ^ 1, (t + 2) * 32);
      bsX = *(const bf16x8*)(pBs + (t + 2) * 32);
      bnX = *(const bf16x8*)(pBn + (t + 2) * 32);
      if (w < 2) asm volatile("s_waitcnt vmcnt(4)" ::: "memory");
      else       asm volatile("s_waitcnt vmcnt(3)" ::: "memory");
    } else {
      asm volatile("s_waitcnt vmcnt(0)" ::: "memory");
    }
    __builtin_amdgcn_s_barrier();
    {
      const bf16_t* aC = (const bf16_t*)(pool + cur * SA_BYTES);
      DS_MFMA(af, bsY, bnY);
    }
    __builtin_amdgcn_s_barrier();
    cur ^= 1;
  }

  // T tile -> per-wave LDS region (pool reuse; fenced by final barrier).
  // C/D layout: col = l&15, row = (l>>4)*4 + reg; strip-5 rows 8..15 dup 0..7.
  float* Tex = (float*)pool;                     // [4 waves][8][20]
  #pragma unroll
  for (int reg = 0; reg < 4; ++reg)
    Tex[(w * 8 + ((kg * 4 + reg) & 7)) * 20 + lr] = acc[5][reg];
  __syncthreads();

  const float bv = bias[n0w + lr];
  #pragma unroll
  for (int s = 0; s < 5; ++s) {
    #pragma unroll
    for (int reg = 0; reg < 4; ++reg) {
      int rloc = s * 16 + kg * 4 + reg;          // 0..79
      int ls = rloc / MAXREL;                    // local sample 0..7
      float v = acc[s][reg] + Tex[(w * 8 + ls) * 20 + lr] + bv;
      out[(size_t)(arow0 + rloc) * D_DIM + n0w + lr] = fmaxf(v, 0.0f);
    }
  }
}

extern "C" void kernel_launch(void* const* d_in, const int* in_sizes, int n_in,
                              void* d_out, int out_size, void* d_ws, size_t ws_size,
                              hipStream_t stream) {
  const float* x     = (const float*)d_in[0];   // [28672, 512]
  const float* Wself = (const float*)d_in[1];   // [512, 512]
  const float* Wnbr  = (const float*)d_in[2];   // [512, 512]
  const float* bias  = (const float*)d_in[3];   // [512]
  const int*   pairs = (const int*)d_in[5];     // [1024, 10, 2]

  char* ws = (char*)d_ws;
  size_t off = 0;
  bf16_t* Sbf = (bf16_t*)(ws + off); off += (size_t)B_SAMP * D_DIM * 2;
  bf16_t* Wst = (bf16_t*)(ws + off); off += (size_t)D_DIM * D_DIM * 2;
  bf16_t* Wnt = (bf16_t*)(ws + off); off += (size_t)D_DIM * D_DIM * 2;
  bf16_t* Abf = (bf16_t*)(ws + off); off += (size_t)OUTROWS * D_DIM * 2;

  prep_kernel<<<B_SAMP + 512, 256, 0, stream>>>(
      x, Wself, Wnbr, pairs, Sbf, Abf, Wst, Wnt);
  fused_gemm_kernel<<<dim3(OUTROWS / 80, D_DIM / 64), 256, 0, stream>>>(
      Abf, Sbf, Wst, Wnt, bias, (float*)d_out);
}